// Round 9
// baseline (227.723 us; speedup 1.0000x reference)
//
#include <hip/hip_runtime.h>
#include <hip/hip_bf16.h>

#define N_NODES 20000
#define N_EDGES 320000
#define IN_DIM  1024
#define H_HEADS 8
#define C_CH    64
#define HC      512
#define LEAKY   0.2f
#define LN_EPS  1e-5f

// Extended (transposed) weight: rows 0..511 = W_src cols, 512..519 = att_src fold,
// 520..527 = att_dst fold, 528..575 zero pad.  wbT[col][k], bf16.
#define BCOLS 576

typedef short bf16x8 __attribute__((ext_vector_type(8)));
typedef float f32x4  __attribute__((ext_vector_type(4)));

__device__ __forceinline__ unsigned short f2bf(float f) {
    union { float f; unsigned int u; } c; c.f = f;
    unsigned int u = c.u;
    unsigned int r = (u + 0x7fffu + ((u >> 16) & 1u)) >> 16;   // RNE
    return (unsigned short)r;
}
__device__ __forceinline__ float bf2f(unsigned int h) {
    union { unsigned int u; float f; } c; c.u = h << 16; return c.f;
}
__device__ __forceinline__ void gload_lds16(const void* g, void* l) {
    __builtin_amdgcn_global_load_lds(
        (const __attribute__((address_space(1))) unsigned int*)g,
        (__attribute__((address_space(3))) unsigned int*)l, 16, 0, 0);
}

// ---------------------------------------------------------------------------
// Fused: blocks [0,1250) do deg histogram; blocks [1250,3298) convert x->bf16.
#define DEG_BLOCKS 1250
#define CONV_BLOCKS 2048

__global__ __launch_bounds__(256) void fused_pre(
        const float* __restrict__ x, short* __restrict__ xb,
        const int* __restrict__ ei, int* __restrict__ deg) {
    int t = threadIdx.x;
    if (blockIdx.x < DEG_BLOCKS) {
        int e = blockIdx.x * 256 + t;                 // 1250*256 == N_EDGES exactly
        atomicAdd(&deg[ei[N_EDGES + e]], 1);
        return;
    }
    int bid = blockIdx.x - DEG_BLOCKS;
    const int total = N_NODES * IN_DIM / 8;
    int stride = CONV_BLOCKS * 256;
    for (int i = bid * 256 + t; i < total; i += stride) {
        float4 a = ((const float4*)x)[(size_t)i * 2];
        float4 b = ((const float4*)x)[(size_t)i * 2 + 1];
        uint4 r;
        r.x = (unsigned int)f2bf(a.x) | ((unsigned int)f2bf(a.y) << 16);
        r.y = (unsigned int)f2bf(a.z) | ((unsigned int)f2bf(a.w) << 16);
        r.z = (unsigned int)f2bf(b.x) | ((unsigned int)f2bf(b.y) << 16);
        r.w = (unsigned int)f2bf(b.z) | ((unsigned int)f2bf(b.w) << 16);
        *(uint4*)(&xb[(size_t)i * 8]) = r;
    }
}

// ---------------------------------------------------------------------------
// Build wbT (bf16, [BCOLS][IN_DIM]).  grid = 1024 prep blocks + 1 scan tail
// block (scan depends only on deg, produced by the previous kernel).
__global__ void prep_w_scan(const float* __restrict__ Wsrc,
                            const float* __restrict__ Wdst,
                            const float* __restrict__ att_src,
                            const float* __restrict__ att_dst,
                            short* __restrict__ wbT,
                            const int* __restrict__ deg,
                            int* __restrict__ off,
                            int* __restrict__ cursor) {
    int t = threadIdx.x;                  // block = 128 threads

    if (blockIdx.x == IN_DIM) {           // ---- scan tail block
        __shared__ int wtot[2];
        int lane = t & 63, w = t >> 6;
        int base = t * 157;               // 128*157 = 20096 >= N_NODES
        int s = 0;
        for (int i = 0; i < 157; ++i) {
            int idx = base + i;
            if (idx < N_NODES) s += deg[idx];
        }
        int v = s;
        #pragma unroll
        for (int o = 1; o < 64; o <<= 1) {
            int u = __shfl_up(v, o);
            if (lane >= o) v += u;
        }
        if (lane == 63) wtot[w] = v;
        __syncthreads();
        int add = (w == 1) ? wtot[0] : 0;
        int run = add + v - s;
        for (int i = 0; i < 157; ++i) {
            int idx = base + i;
            if (idx < N_NODES) {
                off[idx] = run; cursor[idx] = run;
                run += deg[idx];
            }
        }
        if (t == 127) off[N_NODES] = run;
        return;
    }

    int k = blockIdx.x;
    float4 v = *(const float4*)(Wsrc + (size_t)k * HC + t * 4);
    wbT[(size_t)(t * 4 + 0) * IN_DIM + k] = (short)f2bf(v.x);
    wbT[(size_t)(t * 4 + 1) * IN_DIM + k] = (short)f2bf(v.y);
    wbT[(size_t)(t * 4 + 2) * IN_DIM + k] = (short)f2bf(v.z);
    wbT[(size_t)(t * 4 + 3) * IN_DIM + k] = (short)f2bf(v.w);
    if (t < 16) {
        int h = t & 7;
        const float* W   = (t < 8) ? Wsrc : Wdst;
        const float* att = (t < 8) ? att_src : att_dst;
        float s = 0.f;
        #pragma unroll
        for (int c = 0; c < C_CH; ++c)
            s += W[(size_t)k * HC + h * C_CH + c] * att[h * C_CH + c];
        wbT[(size_t)(512 + t) * IN_DIM + k] = (short)f2bf(s);
    } else if (t < 64) {
        wbT[(size_t)(512 + t) * IN_DIM + k] = 0;   // pad cols 528..575
    }
}

// ---------------------------------------------------------------------------
// MFMA GEMM: R3's high-occupancy single-buffer structure (28 KB LDS ->
// 5 blocks/CU LDS-cap; latency hidden by resident-block TLP, m114) combined
// with R8's COALESCED staging + XOR-swizzled chunk layout:
//   LDS slot s = m*8 + kcp holds k-chunk kc = kcp ^ (m&7) of row m (16B chunks)
//   -> staging: 8 consecutive lanes read 128B contiguous (coalesced);
//   -> fragment ds_read_b128: 16 lanes spread over 8 slots = 2-way = free.
// Blocks [0,NWG): GEMM.  Blocks [NWG, NWG+DEG_BLOCKS): edge_scatter (CSR
// scatter fused into this launch; independent of GEMM blocks, fills the
// GEMM's stall slots).
#define BM 128
#define BN 96
#define BK 64
#define NCOLT (BCOLS / BN)                  // 6
#define NROWT ((N_NODES + BM - 1) / BM)     // 157
#define NWG (NCOLT * NROWT)                 // 942
#define KSTEPS (IN_DIM / BK)                // 16
#define A_SLOTS (BM * BK / 8)               // 1024 x 16B = 16 KB
#define B_SLOTS (BN * BK / 8)               // 768  x 16B = 12 KB

__global__ __launch_bounds__(256) void gemm_scatter(
        const short* __restrict__ xb,
        const short* __restrict__ wbT,
        short* __restrict__ xsb,
        float* __restrict__ a_srcv,
        float* __restrict__ a_dstv,
        const int* __restrict__ ei,
        int* __restrict__ cursor,
        int* __restrict__ csr_src) {
    __shared__ short As[A_SLOTS * 8];       // 16 KB
    __shared__ short Bs[B_SLOTS * 8];       // 12 KB  (28 KB total)

    int t = threadIdx.x;

    // ---- scatter blocks: bare CSR scatter, sorted by dst
    if (blockIdx.x >= NWG) {
        int e = (blockIdx.x - NWG) * 256 + t;   // 1250*256 == N_EDGES exactly
        int d = ei[N_EDGES + e];
        int idx = atomicAdd(&cursor[d], 1);
        csr_src[idx] = ei[e];
        return;
    }

    // bijective XCD swizzle (m204): contiguous chunk of wgids per XCD
    int orig = blockIdx.x;
    const int q = NWG >> 3, r = NWG & 7;
    int xcd  = orig & 7;
    int wgid = (xcd < r ? xcd * (q + 1) : r * (q + 1) + (xcd - r) * q) + (orig >> 3);
    int col0 = (wgid % NCOLT) * BN;         // col tiles fastest -> A rows L2-local
    int row0 = (wgid / NCOLT) * BM;

    int lane = t & 63;
    int w    = t >> 6;
    int lr   = lane & 15;
    int lg   = lane >> 4;                   // k-group 0..3
    int sw   = lr & 7;                      // fragment-read swizzle key
    int wr   = (w >> 1) * 64;               // wave row offset (2x2 waves)
    int wc   = (w & 1) * 48;                // wave col offset

    // staging source pointers: A 4 slots/thread, B 3 slots/thread.
    // slot s: m = s>>3, kcp = s&7; source k-chunk kc = kcp ^ (m&7).
    const short* a_base[4];
    #pragma unroll
    for (int i = 0; i < 4; ++i) {
        int s  = t + 256 * i;               // 0..1023
        int m  = s >> 3;
        int kc = (s & 7) ^ (m & 7);
        int gm = row0 + m;
        if (gm >= N_NODES) gm = N_NODES - 1;   // clamp (dead rows, in-bounds)
        a_base[i] = xb + (size_t)gm * IN_DIM + kc * 8;
    }
    const short* b_base[3];
    #pragma unroll
    for (int i = 0; i < 3; ++i) {
        int s  = t + 256 * i;               // 0..767
        int c  = s >> 3;
        int kc = (s & 7) ^ (c & 7);
        b_base[i] = wbT + (size_t)(col0 + c) * IN_DIM + kc * 8;
    }

    f32x4 acc[4][3] = {};

    for (int step = 0; step < KSTEPS; ++step) {
        int k0 = step * BK;
        #pragma unroll
        for (int i = 0; i < 4; ++i)
            gload_lds16(a_base[i] + k0, &As[(t + 256 * i) * 8]);
        #pragma unroll
        for (int i = 0; i < 3; ++i)
            gload_lds16(b_base[i] + k0, &Bs[(t + 256 * i) * 8]);
        asm volatile("s_waitcnt vmcnt(0)" ::: "memory");
        __builtin_amdgcn_s_barrier();

        #pragma unroll
        for (int ks = 0; ks < 2; ++ks) {
            int kc  = ks * 4 + lg;
            int kca = kc ^ sw;              // swizzled chunk index
            bf16x8 af[4], bfr[3];
            #pragma unroll
            for (int mi = 0; mi < 4; ++mi)
                af[mi] = *(const bf16x8*)(&As[((wr + mi * 16 + lr) * 8 + kca) * 8]);
            #pragma unroll
            for (int ni = 0; ni < 3; ++ni)
                bfr[ni] = *(const bf16x8*)(&Bs[((wc + ni * 16 + lr) * 8 + kca) * 8]);
            __builtin_amdgcn_s_setprio(1);
            #pragma unroll
            for (int mi = 0; mi < 4; ++mi)
                #pragma unroll
                for (int ni = 0; ni < 3; ++ni)
                    acc[mi][ni] = __builtin_amdgcn_mfma_f32_16x16x32_bf16(
                        af[mi], bfr[ni], acc[mi][ni], 0, 0, 0);
            __builtin_amdgcn_s_setprio(0);
        }
        __builtin_amdgcn_s_barrier();       // reads done before next overwrite
    }

    // epilogue: C/D layout col=lane&15, row=(lane>>4)*4+reg
    #pragma unroll
    for (int mi = 0; mi < 4; ++mi) {
        #pragma unroll
        for (int rr = 0; rr < 4; ++rr) {
            int row = row0 + wr + mi * 16 + lg * 4 + rr;
            if (row >= N_NODES) continue;
            #pragma unroll
            for (int ni = 0; ni < 3; ++ni) {
                int col = col0 + wc + ni * 16 + lr;
                float v = acc[mi][ni][rr];
                if (col < 512)      xsb[(size_t)row * HC + col] = (short)f2bf(v);
                else if (col < 520) a_srcv[(size_t)row * 8 + (col - 512)] = v;
                else if (col < 528) a_dstv[(size_t)row * 8 + (col - 520)] = v;
            }
        }
    }
}

// ---------------------------------------------------------------------------
// ONE WAVE per destination node (4 independent waves/block, no barriers).
// Lane owns 8 channels of one head: per edge, one dwordx4 gather per lane,
// one weight compute, 8 FMAs.  LN via 6-step shfl_xor across the wave.
__global__ __launch_bounds__(256) void aggregate_ln(
        const int* __restrict__ off,
        const int* __restrict__ csr_src,
        const float* __restrict__ a_srcv,
        const float* __restrict__ a_dstv,
        const short* __restrict__ xsb,
        const float* __restrict__ bias,
        const float* __restrict__ gamma,
        const float* __restrict__ beta,
        const float* __restrict__ prelu_a,
        float* __restrict__ out) {
    int lane = threadIdx.x & 63;
    int n    = blockIdx.x * 4 + (threadIdx.x >> 6);   // grid 5000 x 4 waves = 20000
    int ch0  = lane * 8;
    int h    = lane >> 3;

    int start = off[n], end = off[n + 1];
    float ad  = a_dstv[(size_t)n * 8 + h];

    float acc[8] = {};
    float wsum = 0.f;

    int i = start;
    for (; i + 1 < end; i += 2) {
        int s0 = __builtin_amdgcn_readfirstlane(csr_src[i]);
        int s1 = __builtin_amdgcn_readfirstlane(csr_src[i + 1]);
        float sc0 = a_srcv[(size_t)s0 * 8 + h] + ad;
        float sc1 = a_srcv[(size_t)s1 * 8 + h] + ad;
        uint4 u0 = *(const uint4*)(xsb + (size_t)s0 * HC + ch0);
        uint4 u1 = *(const uint4*)(xsb + (size_t)s1 * HC + ch0);
        sc0 = (sc0 >= 0.f) ? sc0 : LEAKY * sc0;
        sc1 = (sc1 >= 0.f) ? sc1 : LEAKY * sc1;
        float w0 = __expf(sc0);
        float w1 = __expf(sc1);
        acc[0] = fmaf(w0, bf2f(u0.x & 0xffffu), acc[0]);
        acc[1] = fmaf(w0, bf2f(u0.x >> 16),     acc[1]);
        acc[2] = fmaf(w0, bf2f(u0.y & 0xffffu), acc[2]);
        acc[3] = fmaf(w0, bf2f(u0.y >> 16),     acc[3]);
        acc[4] = fmaf(w0, bf2f(u0.z & 0xffffu), acc[4]);
        acc[5] = fmaf(w0, bf2f(u0.z >> 16),     acc[5]);
        acc[6] = fmaf(w0, bf2f(u0.w & 0xffffu), acc[6]);
        acc[7] = fmaf(w0, bf2f(u0.w >> 16),     acc[7]);
        acc[0] = fmaf(w1, bf2f(u1.x & 0xffffu), acc[0]);
        acc[1] = fmaf(w1, bf2f(u1.x >> 16),     acc[1]);
        acc[2] = fmaf(w1, bf2f(u1.y & 0xffffu), acc[2]);
        acc[3] = fmaf(w1, bf2f(u1.y >> 16),     acc[3]);
        acc[4] = fmaf(w1, bf2f(u1.z & 0xffffu), acc[4]);
        acc[5] = fmaf(w1, bf2f(u1.z >> 16),     acc[5]);
        acc[6] = fmaf(w1, bf2f(u1.w & 0xffffu), acc[6]);
        acc[7] = fmaf(w1, bf2f(u1.w >> 16),     acc[7]);
        wsum += w0 + w1;
    }
    if (i < end) {
        int s0 = __builtin_amdgcn_readfirstlane(csr_src[i]);
        float sc0 = a_srcv[(size_t)s0 * 8 + h] + ad;
        uint4 u0 = *(const uint4*)(xsb + (size_t)s0 * HC + ch0);
        sc0 = (sc0 >= 0.f) ? sc0 : LEAKY * sc0;
        float w0 = __expf(sc0);
        acc[0] = fmaf(w0, bf2f(u0.x & 0xffffu), acc[0]);
        acc[1] = fmaf(w0, bf2f(u0.x >> 16),     acc[1]);
        acc[2] = fmaf(w0, bf2f(u0.y & 0xffffu), acc[2]);
        acc[3] = fmaf(w0, bf2f(u0.y >> 16),     acc[3]);
        acc[4] = fmaf(w0, bf2f(u0.z & 0xffffu), acc[4]);
        acc[5] = fmaf(w0, bf2f(u0.z >> 16),     acc[5]);
        acc[6] = fmaf(w0, bf2f(u0.w & 0xffffu), acc[6]);
        acc[7] = fmaf(w0, bf2f(u0.w >> 16),     acc[7]);
        wsum += w0;
    }

    float inv = 1.f / (wsum + 1e-16f);
    float4 b0 = *(const float4*)(bias + ch0);
    float4 b1 = *(const float4*)(bias + ch0 + 4);
    float v8[8];
    float psum = 0.f, psq = 0.f;
    const float bb[8] = {b0.x, b0.y, b0.z, b0.w, b1.x, b1.y, b1.z, b1.w};
    #pragma unroll
    for (int j = 0; j < 8; ++j) {
        v8[j] = acc[j] * inv + bb[j];
        psum += v8[j];
        psq  += v8[j] * v8[j];
    }
    #pragma unroll
    for (int o = 32; o > 0; o >>= 1) {
        psum += __shfl_xor(psum, o);
        psq  += __shfl_xor(psq, o);
    }
    float mu   = psum * (1.f / (float)HC);
    float var  = psq * (1.f / (float)HC) - mu * mu;
    float rstd = rsqrtf(var + LN_EPS);

    float4 g0 = *(const float4*)(gamma + ch0);
    float4 g1 = *(const float4*)(gamma + ch0 + 4);
    float4 e0 = *(const float4*)(beta + ch0);
    float4 e1 = *(const float4*)(beta + ch0 + 4);
    float4 p0 = *(const float4*)(prelu_a + ch0);
    float4 p1 = *(const float4*)(prelu_a + ch0 + 4);
    const float gg[8] = {g0.x, g0.y, g0.z, g0.w, g1.x, g1.y, g1.z, g1.w};
    const float ee[8] = {e0.x, e0.y, e0.z, e0.w, e1.x, e1.y, e1.z, e1.w};
    const float pp[8] = {p0.x, p0.y, p0.z, p0.w, p1.x, p1.y, p1.z, p1.w};
    float y[8];
    #pragma unroll
    for (int j = 0; j < 8; ++j) {
        float v = (v8[j] - mu) * rstd * gg[j] + ee[j];
        y[j] = (v >= 0.f) ? v : pp[j] * v;
    }
    float4* o4 = (float4*)(out + (size_t)n * HC + ch0);
    o4[0] = make_float4(y[0], y[1], y[2], y[3]);
    o4[1] = make_float4(y[4], y[5], y[6], y[7]);
}

// ---------------------------------------------------------------------------
extern "C" void kernel_launch(void* const* d_in, const int* in_sizes, int n_in,
                              void* d_out, int out_size, void* d_ws, size_t ws_size,
                              hipStream_t stream) {
    const float* x        = (const float*)d_in[0];
    const int*   ei       = (const int*)d_in[2];
    const float* Wsrc     = (const float*)d_in[4];
    const float* Wdst     = (const float*)d_in[5];
    const float* att_src  = (const float*)d_in[6];
    const float* att_dst  = (const float*)d_in[7];
    const float* bias     = (const float*)d_in[8];
    const float* gamma    = (const float*)d_in[9];
    const float* beta     = (const float*)d_in[10];
    const float* prelu_a  = (const float*)d_in[11];
    float* out            = (float*)d_out;

    char*  ws = (char*)d_ws;
    size_t o  = 0;
    auto alloc = [&](size_t bytes) -> void* {
        void* p = ws + o;
        o += (bytes + 255) & ~(size_t)255;
        return p;
    };
    short* wbT     = (short*)alloc(sizeof(short) * BCOLS * IN_DIM);        // 1.18 MB
    short* xsb     = (short*)alloc(sizeof(short) * (size_t)N_NODES * HC);  // 20.5 MB
    float* a_srcv  = (float*)alloc(sizeof(float) * N_NODES * 8);
    float* a_dstv  = (float*)alloc(sizeof(float) * N_NODES * 8);
    int*   deg     = (int*)alloc(sizeof(int) * N_NODES);
    int*   off     = (int*)alloc(sizeof(int) * (N_NODES + 1));
    int*   cursor  = (int*)alloc(sizeof(int) * N_NODES);
    int*   csr_src = (int*)alloc(sizeof(int) * N_EDGES);                   // 1.28 MB

    // xb (bf16 x) lives in d_out: exactly N*1024*2B = N*512*4B; d_out is dead
    // until aggregate_ln fully overwrites it.
    short* xb = (short*)d_out;

    hipMemsetAsync(deg, 0, sizeof(int) * N_NODES, stream);

    fused_pre<<<DEG_BLOCKS + CONV_BLOCKS, 256, 0, stream>>>(x, xb, ei, deg);

    // 1024 prep blocks + 1 scan tail block (scan needs deg from fused_pre)
    prep_w_scan<<<IN_DIM + 1, 128, 0, stream>>>(Wsrc, Wdst, att_src, att_dst,
                                                wbT, deg, off, cursor);

    // GEMM blocks + fused edge_scatter blocks (scatter needs cursor from scan)
    gemm_scatter<<<NWG + DEG_BLOCKS, 256, 0, stream>>>(
        xb, wbT, xsb, a_srcv, a_dstv, ei, cursor, csr_src);

    aggregate_ln<<<N_NODES / 4, 256, 0, stream>>>(
        off, csr_src, a_srcv, a_dstv, xsb, bias, gamma, beta, prelu_a, out);
}

// Round 10
// 165.810 us; speedup vs baseline: 1.3734x; 1.3734x over previous
//
#include <hip/hip_runtime.h>
#include <hip/hip_bf16.h>

#define N_NODES 20000
#define N_EDGES 320000
#define IN_DIM  1024
#define H_HEADS 8
#define C_CH    64
#define HC      512
#define LEAKY   0.2f
#define LN_EPS  1e-5f

// Extended (transposed) weight: rows 0..511 = W_src cols, 512..519 = att_src fold,
// 520..527 = att_dst fold, 528..575 zero pad.  wbT[col][k], bf16.
#define BCOLS 576

typedef short bf16x8 __attribute__((ext_vector_type(8)));
typedef float f32x4  __attribute__((ext_vector_type(4)));

__device__ __forceinline__ unsigned short f2bf(float f) {
    union { float f; unsigned int u; } c; c.f = f;
    unsigned int u = c.u;
    unsigned int r = (u + 0x7fffu + ((u >> 16) & 1u)) >> 16;   // RNE
    return (unsigned short)r;
}
__device__ __forceinline__ float bf2f(unsigned int h) {
    union { unsigned int u; float f; } c; c.u = h << 16; return c.f;
}
__device__ __forceinline__ void gload_lds16(const void* g, void* l) {
    __builtin_amdgcn_global_load_lds(
        (const __attribute__((address_space(1))) unsigned int*)g,
        (__attribute__((address_space(3))) unsigned int*)l, 16, 0, 0);
}

// ---------------------------------------------------------------------------
// Fused: blocks [0,1250) do deg histogram; blocks [1250,3298) convert x->bf16.
#define DEG_BLOCKS 1250
#define CONV_BLOCKS 2048

__global__ __launch_bounds__(256) void fused_pre(
        const float* __restrict__ x, short* __restrict__ xb,
        const int* __restrict__ ei, int* __restrict__ deg) {
    int t = threadIdx.x;
    if (blockIdx.x < DEG_BLOCKS) {
        int e = blockIdx.x * 256 + t;                 // 1250*256 == N_EDGES exactly
        atomicAdd(&deg[ei[N_EDGES + e]], 1);
        return;
    }
    int bid = blockIdx.x - DEG_BLOCKS;
    const int total = N_NODES * IN_DIM / 8;
    int stride = CONV_BLOCKS * 256;
    for (int i = bid * 256 + t; i < total; i += stride) {
        float4 a = ((const float4*)x)[(size_t)i * 2];
        float4 b = ((const float4*)x)[(size_t)i * 2 + 1];
        uint4 r;
        r.x = (unsigned int)f2bf(a.x) | ((unsigned int)f2bf(a.y) << 16);
        r.y = (unsigned int)f2bf(a.z) | ((unsigned int)f2bf(a.w) << 16);
        r.z = (unsigned int)f2bf(b.x) | ((unsigned int)f2bf(b.y) << 16);
        r.w = (unsigned int)f2bf(b.z) | ((unsigned int)f2bf(b.w) << 16);
        *(uint4*)(&xb[(size_t)i * 8]) = r;
    }
}

// ---------------------------------------------------------------------------
// Build wbT (bf16, [BCOLS][IN_DIM]).  grid = 1024 prep blocks + 1 scan tail
// block.  Scan is VECTORIZED: 125 threads x 160 elements (40 x int4 loads,
// unrolled -> pipelined), shuffle+LDS scan of per-thread sums, 40 x int4
// prefix stores to off and cursor.  (The old scalar loop-carried scan was
// 83 us — the hidden bottleneck of rounds 3-9.)
__global__ void prep_w_scan(const float* __restrict__ Wsrc,
                            const float* __restrict__ Wdst,
                            const float* __restrict__ att_src,
                            const float* __restrict__ att_dst,
                            short* __restrict__ wbT,
                            const int* __restrict__ deg,
                            int* __restrict__ off,
                            int* __restrict__ cursor) {
    int t = threadIdx.x;                  // block = 128 threads

    if (blockIdx.x == IN_DIM) {           // ---- scan tail block
        __shared__ int wtot[2];
        int lane = t & 63, w = t >> 6;
        const int4* deg4 = (const int4*)deg;
        // pass 1: per-thread sum of 160 elements (40 int4, independent loads)
        int s = 0;
        if (t < 125) {                    // 125*160 == N_NODES exactly
            #pragma unroll
            for (int j = 0; j < 40; ++j) {
                int4 u = deg4[t * 40 + j];
                s += u.x + u.y + u.z + u.w;
            }
        }
        // inclusive shuffle scan within wave, then cross-wave via LDS
        int v = s;
        #pragma unroll
        for (int o = 1; o < 64; o <<= 1) {
            int u = __shfl_up(v, o);
            if (lane >= o) v += u;
        }
        if (lane == 63) wtot[w] = v;
        __syncthreads();
        int add = (w == 1) ? wtot[0] : 0;
        int run = add + v - s;            // exclusive prefix of this segment
        // pass 2: prefix-write (int4 stores; loads are L1/L2 hot)
        if (t < 125) {
            int4* off4 = (int4*)off;
            int4* cur4 = (int4*)cursor;
            #pragma unroll
            for (int j = 0; j < 40; ++j) {
                int4 u = deg4[t * 40 + j];
                int4 o_;
                o_.x = run;
                o_.y = o_.x + u.x;
                o_.z = o_.y + u.y;
                o_.w = o_.z + u.z;
                off4[t * 40 + j] = o_;
                cur4[t * 40 + j] = o_;
                run = o_.w + u.w;
            }
            if (t == 124) off[N_NODES] = run;
        }
        return;
    }

    int k = blockIdx.x;
    float4 v = *(const float4*)(Wsrc + (size_t)k * HC + t * 4);
    wbT[(size_t)(t * 4 + 0) * IN_DIM + k] = (short)f2bf(v.x);
    wbT[(size_t)(t * 4 + 1) * IN_DIM + k] = (short)f2bf(v.y);
    wbT[(size_t)(t * 4 + 2) * IN_DIM + k] = (short)f2bf(v.z);
    wbT[(size_t)(t * 4 + 3) * IN_DIM + k] = (short)f2bf(v.w);
    if (t < 16) {
        int h = t & 7;
        const float* W   = (t < 8) ? Wsrc : Wdst;
        const float* att = (t < 8) ? att_src : att_dst;
        float s = 0.f;
        #pragma unroll
        for (int c = 0; c < C_CH; ++c)
            s += W[(size_t)k * HC + h * C_CH + c] * att[h * C_CH + c];
        wbT[(size_t)(512 + t) * IN_DIM + k] = (short)f2bf(s);
    } else if (t < 64) {
        wbT[(size_t)(512 + t) * IN_DIM + k] = 0;   // pad cols 528..575
    }
}

// ---------------------------------------------------------------------------
// MFMA GEMM: high-occupancy single-buffer structure (28 KB LDS -> 5 blocks/CU
// LDS-cap; latency hidden by resident-block TLP, m114) with COALESCED staging
// + XOR-swizzled chunk layout:
//   LDS slot s = m*8 + kcp holds k-chunk kc = kcp ^ (m&7) of row m (16B chunks)
//   -> staging: 8 consecutive lanes read 128B contiguous (coalesced);
//   -> fragment ds_read_b128: 16 lanes spread over 8 slots = 2-way = free.
// Blocks [0,NWG): GEMM.  Blocks [NWG, NWG+DEG_BLOCKS): edge_scatter (CSR
// scatter fused into this launch; independent of GEMM blocks, fills the
// GEMM's stall slots).
#define BM 128
#define BN 96
#define BK 64
#define NCOLT (BCOLS / BN)                  // 6
#define NROWT ((N_NODES + BM - 1) / BM)     // 157
#define NWG (NCOLT * NROWT)                 // 942
#define KSTEPS (IN_DIM / BK)                // 16
#define A_SLOTS (BM * BK / 8)               // 1024 x 16B = 16 KB
#define B_SLOTS (BN * BK / 8)               // 768  x 16B = 12 KB

__global__ __launch_bounds__(256) void gemm_scatter(
        const short* __restrict__ xb,
        const short* __restrict__ wbT,
        short* __restrict__ xsb,
        float* __restrict__ a_srcv,
        float* __restrict__ a_dstv,
        const int* __restrict__ ei,
        int* __restrict__ cursor,
        int* __restrict__ csr_src) {
    __shared__ short As[A_SLOTS * 8];       // 16 KB
    __shared__ short Bs[B_SLOTS * 8];       // 12 KB  (28 KB total)

    int t = threadIdx.x;

    // ---- scatter blocks: bare CSR scatter, sorted by dst
    if (blockIdx.x >= NWG) {
        int e = (blockIdx.x - NWG) * 256 + t;   // 1250*256 == N_EDGES exactly
        int d = ei[N_EDGES + e];
        int idx = atomicAdd(&cursor[d], 1);
        csr_src[idx] = ei[e];
        return;
    }

    // bijective XCD swizzle (m204): contiguous chunk of wgids per XCD
    int orig = blockIdx.x;
    const int q = NWG >> 3, r = NWG & 7;
    int xcd  = orig & 7;
    int wgid = (xcd < r ? xcd * (q + 1) : r * (q + 1) + (xcd - r) * q) + (orig >> 3);
    int col0 = (wgid % NCOLT) * BN;         // col tiles fastest -> A rows L2-local
    int row0 = (wgid / NCOLT) * BM;

    int lane = t & 63;
    int w    = t >> 6;
    int lr   = lane & 15;
    int lg   = lane >> 4;                   // k-group 0..3
    int sw   = lr & 7;                      // fragment-read swizzle key
    int wr   = (w >> 1) * 64;               // wave row offset (2x2 waves)
    int wc   = (w & 1) * 48;                // wave col offset

    // staging source pointers: A 4 slots/thread, B 3 slots/thread.
    // slot s: m = s>>3, kcp = s&7; source k-chunk kc = kcp ^ (m&7).
    const short* a_base[4];
    #pragma unroll
    for (int i = 0; i < 4; ++i) {
        int s  = t + 256 * i;               // 0..1023
        int m  = s >> 3;
        int kc = (s & 7) ^ (m & 7);
        int gm = row0 + m;
        if (gm >= N_NODES) gm = N_NODES - 1;   // clamp (dead rows, in-bounds)
        a_base[i] = xb + (size_t)gm * IN_DIM + kc * 8;
    }
    const short* b_base[3];
    #pragma unroll
    for (int i = 0; i < 3; ++i) {
        int s  = t + 256 * i;               // 0..767
        int c  = s >> 3;
        int kc = (s & 7) ^ (c & 7);
        b_base[i] = wbT + (size_t)(col0 + c) * IN_DIM + kc * 8;
    }

    f32x4 acc[4][3] = {};

    for (int step = 0; step < KSTEPS; ++step) {
        int k0 = step * BK;
        #pragma unroll
        for (int i = 0; i < 4; ++i)
            gload_lds16(a_base[i] + k0, &As[(t + 256 * i) * 8]);
        #pragma unroll
        for (int i = 0; i < 3; ++i)
            gload_lds16(b_base[i] + k0, &Bs[(t + 256 * i) * 8]);
        asm volatile("s_waitcnt vmcnt(0)" ::: "memory");
        __builtin_amdgcn_s_barrier();

        #pragma unroll
        for (int ks = 0; ks < 2; ++ks) {
            int kc  = ks * 4 + lg;
            int kca = kc ^ sw;              // swizzled chunk index
            bf16x8 af[4], bfr[3];
            #pragma unroll
            for (int mi = 0; mi < 4; ++mi)
                af[mi] = *(const bf16x8*)(&As[((wr + mi * 16 + lr) * 8 + kca) * 8]);
            #pragma unroll
            for (int ni = 0; ni < 3; ++ni)
                bfr[ni] = *(const bf16x8*)(&Bs[((wc + ni * 16 + lr) * 8 + kca) * 8]);
            __builtin_amdgcn_s_setprio(1);
            #pragma unroll
            for (int mi = 0; mi < 4; ++mi)
                #pragma unroll
                for (int ni = 0; ni < 3; ++ni)
                    acc[mi][ni] = __builtin_amdgcn_mfma_f32_16x16x32_bf16(
                        af[mi], bfr[ni], acc[mi][ni], 0, 0, 0);
            __builtin_amdgcn_s_setprio(0);
        }
        __builtin_amdgcn_s_barrier();       // reads done before next overwrite
    }

    // epilogue: C/D layout col=lane&15, row=(lane>>4)*4+reg
    #pragma unroll
    for (int mi = 0; mi < 4; ++mi) {
        #pragma unroll
        for (int rr = 0; rr < 4; ++rr) {
            int row = row0 + wr + mi * 16 + lg * 4 + rr;
            if (row >= N_NODES) continue;
            #pragma unroll
            for (int ni = 0; ni < 3; ++ni) {
                int col = col0 + wc + ni * 16 + lr;
                float v = acc[mi][ni][rr];
                if (col < 512)      xsb[(size_t)row * HC + col] = (short)f2bf(v);
                else if (col < 520) a_srcv[(size_t)row * 8 + (col - 512)] = v;
                else if (col < 528) a_dstv[(size_t)row * 8 + (col - 520)] = v;
            }
        }
    }
}

// ---------------------------------------------------------------------------
// ONE WAVE per destination node (4 independent waves/block, no barriers).
// Lane owns 8 channels of one head: per edge, one dwordx4 gather per lane,
// one weight compute, 8 FMAs.  LN via 6-step shfl_xor across the wave.
__global__ __launch_bounds__(256) void aggregate_ln(
        const int* __restrict__ off,
        const int* __restrict__ csr_src,
        const float* __restrict__ a_srcv,
        const float* __restrict__ a_dstv,
        const short* __restrict__ xsb,
        const float* __restrict__ bias,
        const float* __restrict__ gamma,
        const float* __restrict__ beta,
        const float* __restrict__ prelu_a,
        float* __restrict__ out) {
    int lane = threadIdx.x & 63;
    int n    = blockIdx.x * 4 + (threadIdx.x >> 6);   // grid 5000 x 4 waves = 20000
    int ch0  = lane * 8;
    int h    = lane >> 3;

    int start = off[n], end = off[n + 1];
    float ad  = a_dstv[(size_t)n * 8 + h];

    float acc[8] = {};
    float wsum = 0.f;

    int i = start;
    for (; i + 1 < end; i += 2) {
        int s0 = __builtin_amdgcn_readfirstlane(csr_src[i]);
        int s1 = __builtin_amdgcn_readfirstlane(csr_src[i + 1]);
        float sc0 = a_srcv[(size_t)s0 * 8 + h] + ad;
        float sc1 = a_srcv[(size_t)s1 * 8 + h] + ad;
        uint4 u0 = *(const uint4*)(xsb + (size_t)s0 * HC + ch0);
        uint4 u1 = *(const uint4*)(xsb + (size_t)s1 * HC + ch0);
        sc0 = (sc0 >= 0.f) ? sc0 : LEAKY * sc0;
        sc1 = (sc1 >= 0.f) ? sc1 : LEAKY * sc1;
        float w0 = __expf(sc0);
        float w1 = __expf(sc1);
        acc[0] = fmaf(w0, bf2f(u0.x & 0xffffu), acc[0]);
        acc[1] = fmaf(w0, bf2f(u0.x >> 16),     acc[1]);
        acc[2] = fmaf(w0, bf2f(u0.y & 0xffffu), acc[2]);
        acc[3] = fmaf(w0, bf2f(u0.y >> 16),     acc[3]);
        acc[4] = fmaf(w0, bf2f(u0.z & 0xffffu), acc[4]);
        acc[5] = fmaf(w0, bf2f(u0.z >> 16),     acc[5]);
        acc[6] = fmaf(w0, bf2f(u0.w & 0xffffu), acc[6]);
        acc[7] = fmaf(w0, bf2f(u0.w >> 16),     acc[7]);
        acc[0] = fmaf(w1, bf2f(u1.x & 0xffffu), acc[0]);
        acc[1] = fmaf(w1, bf2f(u1.x >> 16),     acc[1]);
        acc[2] = fmaf(w1, bf2f(u1.y & 0xffffu), acc[2]);
        acc[3] = fmaf(w1, bf2f(u1.y >> 16),     acc[3]);
        acc[4] = fmaf(w1, bf2f(u1.z & 0xffffu), acc[4]);
        acc[5] = fmaf(w1, bf2f(u1.z >> 16),     acc[5]);
        acc[6] = fmaf(w1, bf2f(u1.w & 0xffffu), acc[6]);
        acc[7] = fmaf(w1, bf2f(u1.w >> 16),     acc[7]);
        wsum += w0 + w1;
    }
    if (i < end) {
        int s0 = __builtin_amdgcn_readfirstlane(csr_src[i]);
        float sc0 = a_srcv[(size_t)s0 * 8 + h] + ad;
        uint4 u0 = *(const uint4*)(xsb + (size_t)s0 * HC + ch0);
        sc0 = (sc0 >= 0.f) ? sc0 : LEAKY * sc0;
        float w0 = __expf(sc0);
        acc[0] = fmaf(w0, bf2f(u0.x & 0xffffu), acc[0]);
        acc[1] = fmaf(w0, bf2f(u0.x >> 16),     acc[1]);
        acc[2] = fmaf(w0, bf2f(u0.y & 0xffffu), acc[2]);
        acc[3] = fmaf(w0, bf2f(u0.y >> 16),     acc[3]);
        acc[4] = fmaf(w0, bf2f(u0.z & 0xffffu), acc[4]);
        acc[5] = fmaf(w0, bf2f(u0.z >> 16),     acc[5]);
        acc[6] = fmaf(w0, bf2f(u0.w & 0xffffu), acc[6]);
        acc[7] = fmaf(w0, bf2f(u0.w >> 16),     acc[7]);
        wsum += w0;
    }

    float inv = 1.f / (wsum + 1e-16f);
    float4 b0 = *(const float4*)(bias + ch0);
    float4 b1 = *(const float4*)(bias + ch0 + 4);
    float v8[8];
    float psum = 0.f, psq = 0.f;
    const float bb[8] = {b0.x, b0.y, b0.z, b0.w, b1.x, b1.y, b1.z, b1.w};
    #pragma unroll
    for (int j = 0; j < 8; ++j) {
        v8[j] = acc[j] * inv + bb[j];
        psum += v8[j];
        psq  += v8[j] * v8[j];
    }
    #pragma unroll
    for (int o = 32; o > 0; o >>= 1) {
        psum += __shfl_xor(psum, o);
        psq  += __shfl_xor(psq, o);
    }
    float mu   = psum * (1.f / (float)HC);
    float var  = psq * (1.f / (float)HC) - mu * mu;
    float rstd = rsqrtf(var + LN_EPS);

    float4 g0 = *(const float4*)(gamma + ch0);
    float4 g1 = *(const float4*)(gamma + ch0 + 4);
    float4 e0 = *(const float4*)(beta + ch0);
    float4 e1 = *(const float4*)(beta + ch0 + 4);
    float4 p0 = *(const float4*)(prelu_a + ch0);
    float4 p1 = *(const float4*)(prelu_a + ch0 + 4);
    const float gg[8] = {g0.x, g0.y, g0.z, g0.w, g1.x, g1.y, g1.z, g1.w};
    const float ee[8] = {e0.x, e0.y, e0.z, e0.w, e1.x, e1.y, e1.z, e1.w};
    const float pp[8] = {p0.x, p0.y, p0.z, p0.w, p1.x, p1.y, p1.z, p1.w};
    float y[8];
    #pragma unroll
    for (int j = 0; j < 8; ++j) {
        float v = (v8[j] - mu) * rstd * gg[j] + ee[j];
        y[j] = (v >= 0.f) ? v : pp[j] * v;
    }
    float4* o4 = (float4*)(out + (size_t)n * HC + ch0);
    o4[0] = make_float4(y[0], y[1], y[2], y[3]);
    o4[1] = make_float4(y[4], y[5], y[6], y[7]);
}

// ---------------------------------------------------------------------------
extern "C" void kernel_launch(void* const* d_in, const int* in_sizes, int n_in,
                              void* d_out, int out_size, void* d_ws, size_t ws_size,
                              hipStream_t stream) {
    const float* x        = (const float*)d_in[0];
    const int*   ei       = (const int*)d_in[2];
    const float* Wsrc     = (const float*)d_in[4];
    const float* Wdst     = (const float*)d_in[5];
    const float* att_src  = (const float*)d_in[6];
    const float* att_dst  = (const float*)d_in[7];
    const float* bias     = (const float*)d_in[8];
    const float* gamma    = (const float*)d_in[9];
    const float* beta     = (const float*)d_in[10];
    const float* prelu_a  = (const float*)d_in[11];
    float* out            = (float*)d_out;

    char*  ws = (char*)d_ws;
    size_t o  = 0;
    auto alloc = [&](size_t bytes) -> void* {
        void* p = ws + o;
        o += (bytes + 255) & ~(size_t)255;
        return p;
    };
    short* wbT     = (short*)alloc(sizeof(short) * BCOLS * IN_DIM);        // 1.18 MB
    short* xsb     = (short*)alloc(sizeof(short) * (size_t)N_NODES * HC);  // 20.5 MB
    float* a_srcv  = (float*)alloc(sizeof(float) * N_NODES * 8);
    float* a_dstv  = (float*)alloc(sizeof(float) * N_NODES * 8);
    int*   deg     = (int*)alloc(sizeof(int) * N_NODES);
    int*   off     = (int*)alloc(sizeof(int) * (N_NODES + 1));
    int*   cursor  = (int*)alloc(sizeof(int) * N_NODES);
    int*   csr_src = (int*)alloc(sizeof(int) * N_EDGES);                   // 1.28 MB

    // xb (bf16 x) lives in d_out: exactly N*1024*2B = N*512*4B; d_out is dead
    // until aggregate_ln fully overwrites it.
    short* xb = (short*)d_out;

    hipMemsetAsync(deg, 0, sizeof(int) * N_NODES, stream);

    fused_pre<<<DEG_BLOCKS + CONV_BLOCKS, 256, 0, stream>>>(x, xb, ei, deg);

    // 1024 prep blocks + 1 scan tail block (scan needs deg from fused_pre)
    prep_w_scan<<<IN_DIM + 1, 128, 0, stream>>>(Wsrc, Wdst, att_src, att_dst,
                                                wbT, deg, off, cursor);

    // GEMM blocks + fused edge_scatter blocks (scatter needs cursor from scan)
    gemm_scatter<<<NWG + DEG_BLOCKS, 256, 0, stream>>>(
        xb, wbT, xsb, a_srcv, a_dstv, ei, cursor, csr_src);

    aggregate_ln<<<N_NODES / 4, 256, 0, stream>>>(
        off, csr_src, a_srcv, a_dstv, xsb, bias, gamma, beta, prelu_a, out);
}